// Round 10
// baseline (55.282 us; speedup 1.0000x reference)
//
#include <hip/hip_runtime.h>
#include <math.h>

// DigitCaps2: B=128, C=1024 in_caps, I=16 in_dim, N=16 num_caps, D=16 dim_caps
#define NB 128
#define NC 1024
#define NN 16
#define ND 16
#define NI 16
#define COEF 0.25f

typedef __attribute__((ext_vector_type(8))) short short8;
typedef __attribute__((ext_vector_type(4))) float f32x4;
typedef unsigned short ushort_t;

__device__ __forceinline__ unsigned short f2bf(float f) {
  unsigned int u = __builtin_bit_cast(unsigned int, f);
  u += 0x7fffu + ((u >> 16) & 1u);
  return (unsigned short)(u >> 16);
}

__device__ __forceinline__ short8 cvt8(float4 a, float4 b) {
  short8 o;
  o[0] = (short)f2bf(a.x); o[1] = (short)f2bf(a.y);
  o[2] = (short)f2bf(a.z); o[3] = (short)f2bf(a.w);
  o[4] = (short)f2bf(b.x); o[5] = (short)f2bf(b.y);
  o[6] = (short)f2bf(b.z); o[7] = (short)f2bf(b.w);
  return o;
}

// K1: usum half-partials + on-the-fly f32->bf16 convert of W and x.
// bx = bt*32 + (n*2+h): the 8 bt-blocks sharing a W half-slice share an XCD.
// 16 waves; wave w owns c in [h*512 + w*32, +32) as 4 independent 4-step chains.
// bt==0 blocks store the bf16 W copy; n==0 blocks store the bf16 x copy.
// LDS-reduce 16 waves -> usum2[h][n][b][d].
__global__ __launch_bounds__(1024) void k_usum(const float* __restrict__ xf,
                                               const float* __restrict__ Wf,
                                               ushort_t* __restrict__ xb,
                                               ushort_t* __restrict__ Wb,
                                               float* __restrict__ usum2) {
  __shared__ f32x4 red[16][64];  // 16 KB
  int bx = blockIdx.x;
  int bt = bx >> 5, g = bx & 31;
  int n = g >> 1, h = g & 1;
  int w = threadIdx.x >> 6, l = threadIdx.x & 63;
  int q = l >> 4, b16 = l & 15;
  int c0 = h * 512 + w * 32;
  const bool writeW = (bt == 0);
  const bool writeX = (n == 0);
  f32x4 acc[4];
#pragma unroll
  for (int kk = 0; kk < 4; ++kk) acc[kk] = (f32x4){0.f, 0.f, 0.f, 0.f};
#pragma unroll
  for (int kk = 0; kk < 4; ++kk) {
    size_t wo = (((size_t)(n * NC + c0 + kk * 8 + (q >> 1)) * ND + b16) * NI) + (q & 1) * 8;
    size_t xo = ((size_t)(bt * 16 + b16) * NC + (c0 + kk * 8 + (q >> 1))) * NI + (q & 1) * 8;
#pragma unroll
    for (int s = 0; s < 4; ++s) {
      float4 w0 = *(const float4*)(Wf + wo);
      float4 w1 = *(const float4*)(Wf + wo + 4);
      float4 x0 = *(const float4*)(xf + xo);
      float4 x1 = *(const float4*)(xf + xo + 4);
      short8 av = cvt8(w0, w1);
      short8 bv = cvt8(x0, x1);
      if (writeW) *(short8*)(Wb + wo) = av;
      if (writeX) *(short8*)(xb + xo) = bv;
      acc[kk] = __builtin_amdgcn_mfma_f32_16x16x32_bf16(av, bv, acc[kk], 0, 0, 0);
      wo += 2 * ND * NI;
      xo += 2 * NI;
    }
  }
  red[w][l] = (acc[0] + acc[1]) + (acc[2] + acc[3]);
  __syncthreads();
  if (threadIdx.x < 64) {
    f32x4 t = red[0][l];
#pragma unroll
    for (int k = 1; k < 16; ++k) t += red[k][l];
    *(f32x4*)(usum2 + (((size_t)h * NN + n) * NB + bt * 16 + b16) * ND + q * 4) = t;
  }
}

// K2: fused scores + softmax + weighted-sum. LDS-staged W/x, register u_hat tiles.
// grid = 1024 blocks (bt = bx>>7, cc = bx&127); blocks sharing cc share an XCD
// (bx mod 8 = cc mod 8) so the W slice is fetched from HBM once per XCD.
// 512 threads = 8 waves; wave w handles n = w and n = w+8.
__global__ __launch_bounds__(512, 4) void k_bc(const ushort_t* __restrict__ xb,
                                               const ushort_t* __restrict__ Wb,
                                               const float* __restrict__ usum2,
                                               const float* __restrict__ Bbias,
                                               float* __restrict__ part) {
  __shared__ ushort_t Wl[NN][8][ND][NI];  // 64 KB, [n][c][d][i]
  __shared__ ushort_t xl[16][136];        // x tile [b][c*16+i], padded stride
  __shared__ float scl[NN][8][16];        // 8 KB, [n][c][b16]
  int bx = blockIdx.x;
  int bt = bx >> 7, cc = bx & 127;
  int t = threadIdx.x;
  int w = t >> 6, l = t & 63;
  int q = l >> 4, b16 = l & 15;
  int c0 = cc * 8;
  int n0 = w, n1 = w + 8;

  // usum loads issued first so they overlap the staging burst below
  const float* u0p = usum2 + ((size_t)n0 * NB + bt * 16 + b16) * ND + q * 4;
  f32x4 us0 = *(const f32x4*)u0p + *(const f32x4*)(u0p + (size_t)NN * NB * ND);
  const float* u1p = usum2 + ((size_t)n1 * NB + bt * 16 + b16) * ND + q * 4;
  f32x4 us1 = *(const f32x4*)u1p + *(const f32x4*)(u1p + (size_t)NN * NB * ND);

  // ---- stage W slice: 16 n x (8 c x 256) shorts = 4096 short8 groups ----
  {
    ushort_t* Wflat = &Wl[0][0][0][0];
    const ushort_t* Wsrc = Wb + (size_t)c0 * (ND * NI);
#pragma unroll
    for (int r = 0; r < 8; ++r) {
      int g = r * 512 + t;            // 0..4095
      int n = g >> 8, rem = g & 255;  // 256 short8 per n-chunk (contiguous)
      *(short8*)(Wflat + n * 2048 + rem * 8) =
          *(const short8*)(Wsrc + (size_t)n * (NC * ND * NI) + rem * 8);
    }
    // stage x slice: 16 b x 8 c x 16 i
    if (t < 256) {
      int b = t >> 4, j = t & 15;  // j = c*2 + i-half
      int c = j >> 1, i8 = j & 1;
      *(short8*)(&xl[b][c * 16 + i8 * 8]) =
          *(const short8*)(xb + ((size_t)(bt * 16 + b) * NC + c0 + c) * NI + i8 * 8);
    }
  }
  __syncthreads();

  f32x4 t0[8], t1[8];  // u_hat d-tiles, kept in registers across softmax

  // phase 1a: n0 — u_hat tiles + scores (all operands from LDS)
#pragma unroll
  for (int c = 0; c < 8; ++c) {
    short8 av = {0, 0, 0, 0, 0, 0, 0, 0};
    short8 bv = {0, 0, 0, 0, 0, 0, 0, 0};
    if (q < 2) {
      av = *(const short8*)(&Wl[n0][c][b16][q * 8]);
      bv = *(const short8*)(&xl[b16][c * 16 + q * 8]);
    }
    f32x4 z = {0.f, 0.f, 0.f, 0.f};
    f32x4 d = __builtin_amdgcn_mfma_f32_16x16x32_bf16(av, bv, z, 0, 0, 0);
    t0[c] = d;
    float v = us0[0] * d[0] + us0[1] * d[1] + us0[2] * d[2] + us0[3] * d[3];
    v += __shfl_xor(v, 16);
    v += __shfl_xor(v, 32);
    if (l < 16) scl[n0][c][l] = COEF * v;
  }
  // phase 1b: n1
#pragma unroll
  for (int c = 0; c < 8; ++c) {
    short8 av = {0, 0, 0, 0, 0, 0, 0, 0};
    short8 bv = {0, 0, 0, 0, 0, 0, 0, 0};
    if (q < 2) {
      av = *(const short8*)(&Wl[n1][c][b16][q * 8]);
      bv = *(const short8*)(&xl[b16][c * 16 + q * 8]);
    }
    f32x4 z = {0.f, 0.f, 0.f, 0.f};
    f32x4 d = __builtin_amdgcn_mfma_f32_16x16x32_bf16(av, bv, z, 0, 0, 0);
    t1[c] = d;
    float v = us1[0] * d[0] + us1[1] * d[1] + us1[2] * d[2] + us1[3] * d[3];
    v += __shfl_xor(v, 16);
    v += __shfl_xor(v, 32);
    if (l < 16) scl[n1][c][l] = COEF * v;
  }
  __syncthreads();

  // phase 2: softmax over n + bias (threads < 128; thread owns (c,b) column)
  if (t < 128) {
    int c = t >> 4, b = t & 15;
    float v[NN];
    float m = -1e30f;
#pragma unroll
    for (int k = 0; k < NN; ++k) {
      v[k] = scl[k][c][b];
      m = fmaxf(m, v[k]);
    }
    float sum = 0.f;
#pragma unroll
    for (int k = 0; k < NN; ++k) {
      v[k] = expf(v[k] - m);
      sum += v[k];
    }
    float inv = 1.0f / sum;
#pragma unroll
    for (int k = 0; k < NN; ++k) {
      scl[k][c][b] = v[k] * inv + Bbias[k * NC + c0 + c];
    }
  }
  __syncthreads();

  // phase 3: weighted sum from register tiles
  f32x4 acc0 = {0.f, 0.f, 0.f, 0.f};
  f32x4 acc1 = {0.f, 0.f, 0.f, 0.f};
#pragma unroll
  for (int c = 0; c < 8; ++c) {
    float cf0 = scl[n0][c][b16];
    float cf1 = scl[n1][c][b16];
    acc0[0] = fmaf(cf0, t0[c][0], acc0[0]);
    acc0[1] = fmaf(cf0, t0[c][1], acc0[1]);
    acc0[2] = fmaf(cf0, t0[c][2], acc0[2]);
    acc0[3] = fmaf(cf0, t0[c][3], acc0[3]);
    acc1[0] = fmaf(cf1, t1[c][0], acc1[0]);
    acc1[1] = fmaf(cf1, t1[c][1], acc1[1]);
    acc1[2] = fmaf(cf1, t1[c][2], acc1[2]);
    acc1[3] = fmaf(cf1, t1[c][3], acc1[3]);
  }
  *(f32x4*)(part + ((size_t)((n0 * 8 + bt) * 128 + cc)) * 256 + b16 * 16 + q * 4) = acc0;
  *(f32x4*)(part + ((size_t)((n1 * 8 + bt) * 128 + cc)) * 256 + b16 * 16 + q * 4) = acc1;
}

// K3: reduce s partials over 128 cc + squash -> out[b][n][d].
// 128 blocks (n*8+bt) x 512 threads: thread (hh, t) sums cc in [hh*64,+64) of
// element t of the 256-float (b16,d) tile — fully coalesced 1KB/wave reads.
__global__ __launch_bounds__(512) void k_fin(const float* __restrict__ part,
                                             float* __restrict__ out) {
  __shared__ float red[256];
  int blk = blockIdx.x;  // n*8 + bt
  int n = blk >> 3, bt = blk & 7;
  int tid = threadIdx.x;
  int hh = tid >> 8, t = tid & 255;  // t = b16*16 + d
  const float* pp = part + ((size_t)blk * 128 + hh * 64) * 256 + t;
  float s = 0.f;
#pragma unroll 8
  for (int cc = 0; cc < 64; ++cc) {
    s += *pp;
    pp += 256;
  }
  if (hh) red[t] = s;
  __syncthreads();
  if (tid < 256) {
    float sv = s + red[t];
    float sq = sv * sv;
    sq += __shfl_xor(sq, 1);
    sq += __shfl_xor(sq, 2);
    sq += __shfl_xor(sq, 4);
    sq += __shfl_xor(sq, 8);  // reduce over d within each 16-lane (b16) group
    float norm = sqrtf(sq);
    float scale = (1.0f - expf(-norm)) / sqrtf(sq + 1e-8f);
    int b = bt * 16 + (t >> 4), d = t & 15;
    out[((size_t)b * NN + n) * ND + d] = sv * scale;
  }
}

extern "C" void kernel_launch(void* const* d_in, const int* in_sizes, int n_in,
                              void* d_out, int out_size, void* d_ws, size_t ws_size,
                              hipStream_t stream) {
  const float* x = (const float*)d_in[0];   // [128][1024][16]
  const float* W = (const float*)d_in[1];   // [1][16][1024][16][16]
  const float* Bb = (const float*)d_in[2];  // [16][1][1024]
  float* out = (float*)d_out;               // [128][16][16]
  float* ws = (float*)d_ws;

  // ws layout (float units): ~29.6 MB total
  ushort_t* xb = (ushort_t*)ws;              // 2,097,152 bf16 = 1,048,576 f
  ushort_t* Wb = (ushort_t*)(ws + 1048576);  // 4,194,304 bf16 = 2,097,152 f
  float* part = ws + 1048576 + 2097152;      // [16][8][128][256] = 4,194,304 f
  float* usum2 = part + 4194304;             // [2][16][128][16] = 65,536 f

  hipLaunchKernelGGL(k_usum, dim3(256), dim3(1024), 0, stream, x, W, xb, Wb, usum2);
  hipLaunchKernelGGL(k_bc, dim3(1024), dim3(512), 0, stream, xb, Wb, usum2, Bb, part);
  hipLaunchKernelGGL(k_fin, dim3(128), dim3(512), 0, stream, part, out);
}